// Round 1
// baseline (483.011 us; speedup 1.0000x reference)
//
#include <hip/hip_runtime.h>

#define N_PTS 8192
#define D_DIM 256
#define BN 128
#define BM 128
#define BK 32
#define PAD 4
#define INF_BITS 0x7F800000u

// ---- per-row squared norms: one wave per row, 4 rows per block ----
__global__ void sqnorm_kernel(const float* __restrict__ set1,
                              const float* __restrict__ set2,
                              float* __restrict__ sq1,
                              float* __restrict__ sq2) {
    int wave = threadIdx.x >> 6;
    int lane = threadIdx.x & 63;
    int row = blockIdx.x * 4 + wave;          // 0..16383 combined
    const float* src;
    float* dst;
    int r;
    if (row < N_PTS) { src = set1; dst = sq1; r = row; }
    else             { src = set2; dst = sq2; r = row - N_PTS; }
    // 256 floats per row = 64 lanes x 1 float4
    float4 v = ((const float4*)(src + (size_t)r * D_DIM))[lane];
    float s = v.x * v.x + v.y * v.y + v.z * v.z + v.w * v.w;
    #pragma unroll
    for (int off = 32; off > 0; off >>= 1) s += __shfl_down(s, off, 64);
    if (lane == 0) dst[r] = s;
}

// ---- init min buffers to +inf bit pattern ----
__global__ void init_kernel(unsigned int* __restrict__ rowmin2,
                            unsigned int* __restrict__ colmin2) {
    int i = blockIdx.x * blockDim.x + threadIdx.x;
    if (i < N_PTS) { rowmin2[i] = INF_BITS; colmin2[i] = INF_BITS; }
}

// ---- main tiled kernel: gram + fused d^2 + row/col min ----
__global__ __launch_bounds__(256) void tile_kernel(
    const float* __restrict__ A, const float* __restrict__ B,
    const float* __restrict__ sq1, const float* __restrict__ sq2,
    unsigned int* __restrict__ rowmin2, unsigned int* __restrict__ colmin2) {
    __shared__ float As[BK][BN + PAD];
    __shared__ float Bs[BK][BM + PAD];
    __shared__ unsigned int rmin_s[BN];
    __shared__ unsigned int cmin_s[BM];

    const int tid = threadIdx.x;
    const int tx = tid & 15;   // col group 0..15
    const int ty = tid >> 4;   // row group 0..15
    const int n0 = blockIdx.y * BN;
    const int m0 = blockIdx.x * BM;

    float acc[8][8];
    #pragma unroll
    for (int i = 0; i < 8; i++)
        #pragma unroll
        for (int j = 0; j < 8; j++) acc[i][j] = 0.f;

    for (int k0 = 0; k0 < D_DIM; k0 += BK) {
        // Stage tiles, K-transposed in LDS. 128 rows x 8 float4 = 1024 float4/tile.
        #pragma unroll
        for (int l = 0; l < 4; l++) {
            int f = tid + l * 256;
            int row = f >> 3;
            int c4 = f & 7;
            float4 va = *(const float4*)(A + (size_t)(n0 + row) * D_DIM + k0 + c4 * 4);
            As[c4 * 4 + 0][row] = va.x;
            As[c4 * 4 + 1][row] = va.y;
            As[c4 * 4 + 2][row] = va.z;
            As[c4 * 4 + 3][row] = va.w;
            float4 vb = *(const float4*)(B + (size_t)(m0 + row) * D_DIM + k0 + c4 * 4);
            Bs[c4 * 4 + 0][row] = vb.x;
            Bs[c4 * 4 + 1][row] = vb.y;
            Bs[c4 * 4 + 2][row] = vb.z;
            Bs[c4 * 4 + 3][row] = vb.w;
        }
        __syncthreads();
        #pragma unroll
        for (int k = 0; k < BK; k++) {
            float a[8], b[8];
            #pragma unroll
            for (int i = 0; i < 8; i++) a[i] = As[k][ty * 8 + i];
            #pragma unroll
            for (int j = 0; j < 8; j++) b[j] = Bs[k][tx * 8 + j];
            #pragma unroll
            for (int i = 0; i < 8; i++)
                #pragma unroll
                for (int j = 0; j < 8; j++)
                    acc[i][j] = fmaf(a[i], b[j], acc[i][j]);
        }
        __syncthreads();
    }

    // Epilogue: d^2 = sq1 + sq2 - 2*gram, clamp >= 0; track row/col mins of d^2.
    if (tid < BN) { rmin_s[tid] = INF_BITS; cmin_s[tid] = INF_BITS; }
    __syncthreads();

    float sqr[8], sqc[8];
    #pragma unroll
    for (int i = 0; i < 8; i++) sqr[i] = sq1[n0 + ty * 8 + i];
    #pragma unroll
    for (int j = 0; j < 8; j++) sqc[j] = sq2[m0 + tx * 8 + j];

    float rmin[8], cmin[8];
    #pragma unroll
    for (int i = 0; i < 8; i++) { rmin[i] = __uint_as_float(INF_BITS); cmin[i] = __uint_as_float(INF_BITS); }
    #pragma unroll
    for (int i = 0; i < 8; i++)
        #pragma unroll
        for (int j = 0; j < 8; j++) {
            float d2 = fmaxf(sqr[i] + sqc[j] - 2.f * acc[i][j], 0.f);
            rmin[i] = fminf(rmin[i], d2);
            cmin[j] = fminf(cmin[j], d2);
        }
    #pragma unroll
    for (int i = 0; i < 8; i++) {
        atomicMin(&rmin_s[ty * 8 + i], __float_as_uint(rmin[i]));
        atomicMin(&cmin_s[tx * 8 + i], __float_as_uint(cmin[i]));
    }
    __syncthreads();
    if (tid < BN) atomicMin(&rowmin2[n0 + tid], rmin_s[tid]);
    else          atomicMin(&colmin2[m0 + tid - BN], cmin_s[tid - BN]);
}

// ---- final reduction: mean(sqrt(rowmin2)) + mean(sqrt(colmin2)) ----
__global__ void reduce_kernel(const unsigned int* __restrict__ rowmin2,
                              const unsigned int* __restrict__ colmin2,
                              float* __restrict__ out) {
    float s = 0.f;
    for (int i = threadIdx.x; i < N_PTS; i += blockDim.x) {
        s += sqrtf(__uint_as_float(rowmin2[i]));
        s += sqrtf(__uint_as_float(colmin2[i]));
    }
    #pragma unroll
    for (int off = 32; off > 0; off >>= 1) s += __shfl_down(s, off, 64);
    __shared__ float ws[4];
    int lane = threadIdx.x & 63, wave = threadIdx.x >> 6;
    if (lane == 0) ws[wave] = s;
    __syncthreads();
    if (threadIdx.x == 0) out[0] = (ws[0] + ws[1] + ws[2] + ws[3]) / (float)N_PTS;
}

extern "C" void kernel_launch(void* const* d_in, const int* in_sizes, int n_in,
                              void* d_out, int out_size, void* d_ws, size_t ws_size,
                              hipStream_t stream) {
    const float* set1 = (const float*)d_in[0];
    const float* set2 = (const float*)d_in[1];
    float* out = (float*)d_out;

    float* sq1 = (float*)d_ws;
    float* sq2 = sq1 + N_PTS;
    unsigned int* rowmin2 = (unsigned int*)(sq2 + N_PTS);
    unsigned int* colmin2 = rowmin2 + N_PTS;

    init_kernel<<<(N_PTS + 255) / 256, 256, 0, stream>>>(rowmin2, colmin2);
    sqnorm_kernel<<<(2 * N_PTS) / 4, 256, 0, stream>>>(set1, set2, sq1, sq2);
    tile_kernel<<<dim3(N_PTS / BM, N_PTS / BN), 256, 0, stream>>>(
        set1, set2, sq1, sq2, rowmin2, colmin2);
    reduce_kernel<<<1, 256, 0, stream>>>(rowmin2, colmin2, out);
}

// Round 2
// 139.735 us; speedup vs baseline: 3.4566x; 3.4566x over previous
//
#include <hip/hip_runtime.h>

#define N_PTS 8192
#define D_DIM 256
#define BT 128
#define BK 32
#define INF_BITS 0x7F800000u

typedef __attribute__((ext_vector_type(8))) short short8;
typedef __attribute__((ext_vector_type(4))) float f32x4;

// async global->LDS, 16B per lane; LDS dest = wave-uniform base + lane*16
__device__ __forceinline__ void gload_lds16(const ushort* g, ushort* l) {
    __builtin_amdgcn_global_load_lds(
        (const __attribute__((address_space(1))) void*)g,
        (__attribute__((address_space(3))) void*)l, 16, 0, 0);
}

__device__ __forceinline__ ushort f2bf(float x) {
    unsigned u = __float_as_uint(x);
    return (ushort)((u + 0x7FFFu + ((u >> 16) & 1u)) >> 16);  // RNE, no NaN inputs
}

// ---- fp32 -> bf16 conversion for both sets (8 elems/thread) ----
__global__ void convert_kernel(const float* __restrict__ s1,
                               const float* __restrict__ s2,
                               ushort* __restrict__ b1,
                               ushort* __restrict__ b2) {
    const int half = N_PTS * D_DIM;
    int i = (blockIdx.x * 256 + threadIdx.x) * 8;
    const float* src; ushort* dst; int off;
    if (i < half) { src = s1; dst = b1; off = i; }
    else          { src = s2; dst = b2; off = i - half; }
    float4 v0 = *(const float4*)(src + off);
    float4 v1 = *(const float4*)(src + off + 4);
    ushort4 o0 = { f2bf(v0.x), f2bf(v0.y), f2bf(v0.z), f2bf(v0.w) };
    ushort4 o1 = { f2bf(v1.x), f2bf(v1.y), f2bf(v1.z), f2bf(v1.w) };
    *(ushort4*)(dst + off)     = o0;
    *(ushort4*)(dst + off + 4) = o1;
}

// ---- per-row squared norms (fp32 exact): one wave per row ----
__global__ void sqnorm_kernel(const float* __restrict__ set1,
                              const float* __restrict__ set2,
                              float* __restrict__ sq1,
                              float* __restrict__ sq2) {
    int wave = threadIdx.x >> 6;
    int lane = threadIdx.x & 63;
    int row = blockIdx.x * 4 + wave;
    const float* src; float* dst; int r;
    if (row < N_PTS) { src = set1; dst = sq1; r = row; }
    else             { src = set2; dst = sq2; r = row - N_PTS; }
    float4 v = ((const float4*)(src + (size_t)r * D_DIM))[lane];
    float s = v.x * v.x + v.y * v.y + v.z * v.z + v.w * v.w;
    #pragma unroll
    for (int off = 32; off > 0; off >>= 1) s += __shfl_down(s, off, 64);
    if (lane == 0) dst[r] = s;
}

__global__ void init_kernel(unsigned int* __restrict__ rowmin2,
                            unsigned int* __restrict__ colmin2) {
    int i = blockIdx.x * blockDim.x + threadIdx.x;
    if (i < N_PTS) { rowmin2[i] = INF_BITS; colmin2[i] = INF_BITS; }
}

// ---- MFMA gram + fused d^2 + row/col min ----
__global__ __launch_bounds__(256) void tile_kernel(
    const ushort* __restrict__ B1, const ushort* __restrict__ B2,
    const float* __restrict__ sq1, const float* __restrict__ sq2,
    unsigned int* __restrict__ rowmin2, unsigned int* __restrict__ colmin2) {
    // unpadded row-major [128][32] bf16 tiles (global_load_lds requires linear layout)
    __shared__ ushort As[BT * BK] __attribute__((aligned(16)));
    __shared__ ushort Bs[BT * BK] __attribute__((aligned(16)));
    __shared__ unsigned int rs[BT];
    __shared__ unsigned int cs[BT];

    const int tid  = threadIdx.x;
    const int lane = tid & 63;
    const int w    = tid >> 6;
    const int quad = lane >> 4;
    const int c    = lane & 15;
    const int n_off = (w >> 1) * 64;   // wave's 64x64 quadrant
    const int m_off = (w & 1) * 64;
    const int n0 = blockIdx.y * BT;
    const int m0 = blockIdx.x * BT;

    if (tid < BT) { rs[tid] = INF_BITS; cs[tid] = INF_BITS; }

    f32x4 acc[4][4];
    #pragma unroll
    for (int ti = 0; ti < 4; ti++)
        #pragma unroll
        for (int tj = 0; tj < 4; tj++) acc[ti][tj] = (f32x4){0.f, 0.f, 0.f, 0.f};

    for (int k0 = 0; k0 < D_DIM; k0 += BK) {
        // stage: 128 rows x 32 bf16 = 512 x 16B chunks per matrix, 2 per thread
        #pragma unroll
        for (int ch = 0; ch < 2; ch++) {
            int idx = ch * 256 + tid;
            int row = idx >> 2;          // 4 x 16B chunks per 32-elem row
            int c4  = idx & 3;
            gload_lds16(B1 + (size_t)(n0 + row) * D_DIM + k0 + c4 * 8,
                        &As[(idx & ~63) * 8]);
            gload_lds16(B2 + (size_t)(m0 + row) * D_DIM + k0 + c4 * 8,
                        &Bs[(idx & ~63) * 8]);
        }
        __syncthreads();

        short8 a[4], b[4];
        #pragma unroll
        for (int ti = 0; ti < 4; ti++)
            a[ti] = *(const short8*)&As[(n_off + ti * 16 + c) * BK + quad * 8];
        #pragma unroll
        for (int tj = 0; tj < 4; tj++)
            b[tj] = *(const short8*)&Bs[(m_off + tj * 16 + c) * BK + quad * 8];
        #pragma unroll
        for (int ti = 0; ti < 4; ti++)
            #pragma unroll
            for (int tj = 0; tj < 4; tj++)
                acc[ti][tj] = __builtin_amdgcn_mfma_f32_16x16x32_bf16(
                    a[ti], b[tj], acc[ti][tj], 0, 0, 0);
        __syncthreads();
    }

    // epilogue: d2 = sq1[n] + sq2[m] - 2*gram; C/D layout col=lane&15, row=quad*4+reg
    float sqn[4][4], sqm[4];
    #pragma unroll
    for (int ti = 0; ti < 4; ti++)
        #pragma unroll
        for (int r = 0; r < 4; r++)
            sqn[ti][r] = sq1[n0 + n_off + ti * 16 + quad * 4 + r];
    #pragma unroll
    for (int tj = 0; tj < 4; tj++)
        sqm[tj] = sq2[m0 + m_off + tj * 16 + c];

    float rmin[4][4], cmin[4];
    #pragma unroll
    for (int ti = 0; ti < 4; ti++)
        #pragma unroll
        for (int r = 0; r < 4; r++) rmin[ti][r] = __uint_as_float(INF_BITS);
    #pragma unroll
    for (int tj = 0; tj < 4; tj++) cmin[tj] = __uint_as_float(INF_BITS);

    #pragma unroll
    for (int ti = 0; ti < 4; ti++)
        #pragma unroll
        for (int tj = 0; tj < 4; tj++)
            #pragma unroll
            for (int r = 0; r < 4; r++) {
                float d2 = fmaxf(sqn[ti][r] + sqm[tj] - 2.f * acc[ti][tj][r], 0.f);
                rmin[ti][r] = fminf(rmin[ti][r], d2);
                cmin[tj]    = fminf(cmin[tj], d2);
            }

    // row mins: reduce over the 16 lanes of each quad (c dimension)
    #pragma unroll
    for (int m = 1; m <= 8; m <<= 1)
        #pragma unroll
        for (int ti = 0; ti < 4; ti++)
            #pragma unroll
            for (int r = 0; r < 4; r++)
                rmin[ti][r] = fminf(rmin[ti][r], __shfl_xor(rmin[ti][r], m, 64));
    // col mins: reduce over the 4 quads
    #pragma unroll
    for (int m = 16; m <= 32; m <<= 1)
        #pragma unroll
        for (int tj = 0; tj < 4; tj++)
            cmin[tj] = fminf(cmin[tj], __shfl_xor(cmin[tj], m, 64));

    if (c == 0) {
        #pragma unroll
        for (int ti = 0; ti < 4; ti++)
            #pragma unroll
            for (int r = 0; r < 4; r++)
                atomicMin(&rs[n_off + ti * 16 + quad * 4 + r],
                          __float_as_uint(rmin[ti][r]));
    }
    if (quad == 0) {
        #pragma unroll
        for (int tj = 0; tj < 4; tj++)
            atomicMin(&cs[m_off + tj * 16 + c], __float_as_uint(cmin[tj]));
    }
    __syncthreads();
    if (tid < BT) atomicMin(&rowmin2[n0 + tid], rs[tid]);
    else          atomicMin(&colmin2[m0 + tid - BT], cs[tid - BT]);
}

// ---- final: mean(sqrt(rowmin2)) + mean(sqrt(colmin2)) ----
__global__ void reduce_kernel(const unsigned int* __restrict__ rowmin2,
                              const unsigned int* __restrict__ colmin2,
                              float* __restrict__ out) {
    float s = 0.f;
    for (int i = threadIdx.x; i < N_PTS; i += blockDim.x) {
        s += sqrtf(__uint_as_float(rowmin2[i]));
        s += sqrtf(__uint_as_float(colmin2[i]));
    }
    #pragma unroll
    for (int off = 32; off > 0; off >>= 1) s += __shfl_down(s, off, 64);
    __shared__ float ws[4];
    int lane = threadIdx.x & 63, wave = threadIdx.x >> 6;
    if (lane == 0) ws[wave] = s;
    __syncthreads();
    if (threadIdx.x == 0) out[0] = (ws[0] + ws[1] + ws[2] + ws[3]) / (float)N_PTS;
}

extern "C" void kernel_launch(void* const* d_in, const int* in_sizes, int n_in,
                              void* d_out, int out_size, void* d_ws, size_t ws_size,
                              hipStream_t stream) {
    const float* set1 = (const float*)d_in[0];
    const float* set2 = (const float*)d_in[1];
    float* out = (float*)d_out;

    // workspace layout (all 16B aligned)
    unsigned int* rowmin2 = (unsigned int*)d_ws;            // 32 KB
    unsigned int* colmin2 = rowmin2 + N_PTS;                // 32 KB
    float* sq1 = (float*)(colmin2 + N_PTS);                 // 32 KB
    float* sq2 = sq1 + N_PTS;                               // 32 KB
    ushort* b1 = (ushort*)(sq2 + N_PTS);                    // 4 MB
    ushort* b2 = b1 + (size_t)N_PTS * D_DIM;                // 4 MB

    init_kernel<<<(N_PTS + 255) / 256, 256, 0, stream>>>(rowmin2, colmin2);
    sqnorm_kernel<<<(2 * N_PTS) / 4, 256, 0, stream>>>(set1, set2, sq1, sq2);
    convert_kernel<<<(2 * N_PTS * D_DIM) / (256 * 8), 256, 0, stream>>>(
        set1, set2, b1, b2);
    tile_kernel<<<dim3(N_PTS / BT, N_PTS / BT), 256, 0, stream>>>(
        b1, b2, sq1, sq2, rowmin2, colmin2);
    reduce_kernel<<<1, 256, 0, stream>>>(rowmin2, colmin2, out);
}